// Round 4
// baseline (376.150 us; speedup 1.0000x reference)
//
#include <hip/hip_runtime.h>
#include <hip/hip_bf16.h>

// GraphSAGE 2-layer, fused bf16-MFMA version (7 dispatches).
// sage(feat) = mean_agg(feat) @ Wl^T + feat @ Wr^T + b
// Per layer ONE kernel: gather-mean into LDS A-tile -> dual GEMM
// ([N,256]@[256,128], K = agg(128)||feat(128)) with v_mfma_f32_16x16x32_bf16.

#define D 128
#define SCAN_BLK 1024

typedef __attribute__((ext_vector_type(8))) short bf16x8;
typedef __attribute__((ext_vector_type(4))) float f32x4;

__device__ inline ushort f2bf(float f) {
    uint u = __float_as_uint(f);
    u += 0x7FFF + ((u >> 16) & 1);            // round-to-nearest-even
    return (ushort)(u >> 16);
}

// ---------------- setup: count_deg + x->bf16 + pack both weight tables ----------

__global__ __launch_bounds__(256) void setup_all(
        const float* __restrict__ x, const int* __restrict__ ei,
        const float* __restrict__ W1l, const float* __restrict__ W1r,
        const float* __restrict__ W2l, const float* __restrict__ W2r,
        ushort* __restrict__ xb, ushort* __restrict__ wcat1,
        ushort* __restrict__ wcat2, int* __restrict__ deg,
        int n8, int E, int nb_cvt, int nb_cnt) {
    int b = blockIdx.x;
    int tid = threadIdx.x;
    if (b < nb_cvt) {
        // x (f32) -> xb (bf16), 8 elems/thread
        int i = b * 256 + tid;
        if (i >= n8) return;
        const float4* p = (const float4*)x;
        float4 a = p[i * 2], c = p[i * 2 + 1];
        uint4 pk;
        pk.x = (uint)f2bf(a.x) | ((uint)f2bf(a.y) << 16);
        pk.y = (uint)f2bf(a.z) | ((uint)f2bf(a.w) << 16);
        pk.z = (uint)f2bf(c.x) | ((uint)f2bf(c.y) << 16);
        pk.w = (uint)f2bf(c.z) | ((uint)f2bf(c.w) << 16);
        *(uint4*)&xb[i * 8] = pk;
    } else if (b < nb_cvt + nb_cnt) {
        // degree count (dst)
        int e = (b - nb_cvt) * 256 + tid;
        if (e < E) atomicAdd(&deg[ei[E + e]], 1);
    } else {
        // pack Wl||Wr -> wcat[128][256] bf16, both layers. 16384 threads, 4 elems each.
        int t = (b - nb_cvt - nb_cnt) * 256 + tid;
        int layer = t >> 13;                  // 0 or 1
        int tt = t & 8191;
        int e = tt * 4;
        int row = e >> 8;
        int k = e & 255;
        const float* Wl = layer ? W2l : W1l;
        const float* Wr = layer ? W2r : W1r;
        const float* src = (k < 128) ? &Wl[row * 128 + k] : &Wr[row * 128 + k - 128];
        float4 v = *(const float4*)src;
        uint2 pk;
        pk.x = (uint)f2bf(v.x) | ((uint)f2bf(v.y) << 16);
        pk.y = (uint)f2bf(v.z) | ((uint)f2bf(v.w) << 16);
        ushort* wcat = layer ? wcat2 : wcat1;
        *(uint2*)&wcat[e] = pk;
    }
}

// ---------------- CSR scan ----------------

__global__ __launch_bounds__(SCAN_BLK) void scan_local(
        const int* __restrict__ deg, int* __restrict__ rowptr,
        int* __restrict__ partials, int n) {
    __shared__ int sdata[SCAN_BLK];
    int tid = threadIdx.x;
    int i = blockIdx.x * SCAN_BLK + tid;
    int v = (i < n) ? deg[i] : 0;
    sdata[tid] = v;
    __syncthreads();
    #pragma unroll
    for (int off = 1; off < SCAN_BLK; off <<= 1) {
        int t = (tid >= off) ? sdata[tid - off] : 0;
        __syncthreads();
        sdata[tid] += t;
        __syncthreads();
    }
    if (i < n) rowptr[i] = sdata[tid] - v;              // local exclusive
    if (tid == SCAN_BLK - 1) partials[blockIdx.x] = sdata[SCAN_BLK - 1];
}

__global__ __launch_bounds__(256) void scan_fin(
        int* __restrict__ rowptr, const int* __restrict__ partials,
        int nchunks, int n) {
    __shared__ int p[1024];
    int tid = threadIdx.x;
    for (int j = tid; j < nchunks; j += 256) p[j] = partials[j];
    __syncthreads();
    int i = blockIdx.x * 256 + tid;
    if (i > n) return;
    if (i == n) {
        int t = 0;
        for (int j = 0; j < nchunks; ++j) t += p[j];
        rowptr[n] = t;
    } else {
        int c = i >> 10;
        int base = 0;
        for (int j = 0; j < c; ++j) base += p[j];
        rowptr[i] += base;
    }
}

__global__ void fill_csr(const int* __restrict__ ei, int* __restrict__ cursor,
                         const int* __restrict__ rowptr, int* __restrict__ csr, int E) {
    int e = blockIdx.x * 256 + threadIdx.x;
    if (e < E) {
        int s = ei[e];          // src
        int d = ei[E + e];      // dst
        int pos = atomicAdd(&cursor[d], 1);
        csr[rowptr[d] + pos] = s;
    }
}

// ---------------- fused sage layer: gather-mean (LDS) + dual MFMA GEMM ----------
// Block: 256 thr (4 waves), 128 nodes. Phase 1: 8 half-waves gather-mean 16 nodes
// each (8 loads in flight), f32 accum, bf16 into swizzled LDS A-tile [128][128].
// Phase 2: wave w owns rows w*32..+31 x 128 cols. kc 0..3: A from LDS (agg),
// kc 4..7: A from global featb. B-frags from global wcat (64KB, L1/L2-hot).
// Swizzle byte ^= (row&7)<<4 : row stride 256B else 16-way conflict on b128 reads.

template <bool OUT_BF16, bool RELU>
__global__ __launch_bounds__(256) void sage_layer(
        const ushort* __restrict__ featb, const int* __restrict__ rowptr,
        const int* __restrict__ csr, const ushort* __restrict__ wcat,
        const float* __restrict__ bias, void* __restrict__ outp, int n) {
    __shared__ char lds[32768];        // A-tile [128 rows][128 dims] bf16, swizzled
    int tid = threadIdx.x;
    int blk = blockIdx.x;

    // ---- phase 1: gather-mean ----
    {
        int hw = tid >> 5, lane = tid & 31;
        for (int sub = 0; sub < 16; ++sub) {
            int lr = hw + sub * 8;              // local row 0..127
            int g = blk * 128 + lr;
            float a0 = 0.f, a1 = 0.f, a2 = 0.f, a3 = 0.f;
            if (g < n) {
                int beg = rowptr[g], end = rowptr[g + 1];
                for (int e = beg; e < end; e += 8) {
                    uint2 v[8];
                    float w[8];
                    #pragma unroll
                    for (int u = 0; u < 8; ++u) {
                        int idx = e + u;
                        int safe = (idx < end) ? idx : beg;
                        int s = csr[safe];
                        v[u] = *(const uint2*)&featb[s * D + lane * 4];
                        w[u] = (idx < end) ? 1.f : 0.f;
                    }
                    #pragma unroll
                    for (int u = 0; u < 8; ++u) {
                        a0 = fmaf(w[u], __uint_as_float(v[u].x << 16), a0);
                        a1 = fmaf(w[u], __uint_as_float(v[u].x & 0xFFFF0000u), a1);
                        a2 = fmaf(w[u], __uint_as_float(v[u].y << 16), a2);
                        a3 = fmaf(w[u], __uint_as_float(v[u].y & 0xFFFF0000u), a3);
                    }
                }
                float inv = (end > beg) ? 1.0f / (float)(end - beg) : 0.0f;
                a0 *= inv; a1 *= inv; a2 *= inv; a3 *= inv;
            }
            uint2 pk;
            pk.x = (uint)f2bf(a0) | ((uint)f2bf(a1) << 16);
            pk.y = (uint)f2bf(a2) | ((uint)f2bf(a3) << 16);
            int byte = (lr << 8) + lane * 8;
            *(uint2*)&lds[byte ^ ((lr & 7) << 4)] = pk;
        }
    }
    __syncthreads();

    // ---- phase 2: dual GEMM ----
    int wave = tid >> 6, l = tid & 63;
    int l15 = l & 15, lhi = l >> 4;
    int row_base = blk * 128 + wave * 32;

    f32x4 zero = {0.f, 0.f, 0.f, 0.f};
    f32x4 acc[2][8];
    #pragma unroll
    for (int t = 0; t < 2; ++t)
        #pragma unroll
        for (int j = 0; j < 8; ++j) acc[t][j] = zero;

    int ra0 = row_base + l15;       if (ra0 > n - 1) ra0 = n - 1;
    int ra1 = row_base + 16 + l15;  if (ra1 > n - 1) ra1 = n - 1;
    int lr0 = wave * 32 + l15, lr1 = lr0 + 16;

    #pragma unroll
    for (int kc = 0; kc < 8; ++kc) {
        bf16x8 a0, a1;
        if (kc < 4) {
            int b0 = (lr0 << 8) + kc * 64 + lhi * 16;
            int b1 = (lr1 << 8) + kc * 64 + lhi * 16;
            a0 = *(const bf16x8*)&lds[b0 ^ ((lr0 & 7) << 4)];
            a1 = *(const bf16x8*)&lds[b1 ^ ((lr1 & 7) << 4)];
        } else {
            int klocal = (kc - 4) * 32 + lhi * 8;
            a0 = *(const bf16x8*)&featb[ra0 * D + klocal];
            a1 = *(const bf16x8*)&featb[ra1 * D + klocal];
        }
        #pragma unroll
        for (int j = 0; j < 8; ++j) {
            bf16x8 b = *(const bf16x8*)&wcat[(l15 + j * 16) * 256 + kc * 32 + lhi * 8];
            acc[0][j] = __builtin_amdgcn_mfma_f32_16x16x32_bf16(a0, b, acc[0][j], 0, 0, 0);
            acc[1][j] = __builtin_amdgcn_mfma_f32_16x16x32_bf16(a1, b, acc[1][j], 0, 0, 0);
        }
    }

    // epilogue: C/D layout col = lane&15, row = (lane>>4)*4 + reg
    #pragma unroll
    for (int t = 0; t < 2; ++t) {
        #pragma unroll
        for (int j = 0; j < 8; ++j) {
            int col = j * 16 + l15;
            float bv = bias[col];
            #pragma unroll
            for (int r = 0; r < 4; ++r) {
                int grow = row_base + t * 16 + lhi * 4 + r;
                if (grow >= n) continue;
                float v = acc[t][j][r] + bv;
                if (RELU) v = fmaxf(v, 0.f);
                if (OUT_BF16) ((ushort*)outp)[grow * D + col] = f2bf(v);
                else          ((float*)outp)[grow * D + col] = v;
            }
        }
    }
}

// ---------------- launch ----------------

extern "C" void kernel_launch(void* const* d_in, const int* in_sizes, int n_in,
                              void* d_out, int out_size, void* d_ws, size_t ws_size,
                              hipStream_t stream) {
    const float* x   = (const float*)d_in[0];
    const int*   ei  = (const int*)d_in[1];
    const float* W1l = (const float*)d_in[2];
    const float* b1  = (const float*)d_in[3];
    const float* W1r = (const float*)d_in[4];
    const float* W2l = (const float*)d_in[5];
    const float* b2  = (const float*)d_in[6];
    const float* W2r = (const float*)d_in[7];
    float* out = (float*)d_out;

    const int N = in_sizes[0] / D;
    const int E = in_sizes[1] / 2;

    // workspace layout
    ushort* xb    = (ushort*)d_ws;                        // N*D bf16
    ushort* hbuf  = xb + (size_t)N * D;                   // N*D bf16
    ushort* wcat1 = hbuf + (size_t)N * D;                 // 32768 bf16
    ushort* wcat2 = wcat1 + 32768;                        // 32768 bf16
    int* deg      = (int*)(wcat2 + 32768);                // N
    int* cursor   = deg + N;                              // N (adjacent: 1 memset)
    int* rowptr   = cursor + N;                           // N+1
    int* csr      = rowptr + N + 1;                       // E
    int* parts    = csr + E;                              // 1024

    const int nchunks = (N + SCAN_BLK - 1) / SCAN_BLK;
    const int eblk = (E + 255) / 256;
    const int n8 = N * D / 8;
    const int nb_cvt = (n8 + 255) / 256;
    const int nb_cnt = eblk;
    const int nb_w = 16384 / 256;   // 2 layers * 32768 elems / 4 per thread / 256

    hipMemsetAsync(deg, 0, 2 * (size_t)N * sizeof(int), stream);   // deg + cursor

    setup_all<<<nb_cvt + nb_cnt + nb_w, 256, 0, stream>>>(
        x, ei, W1l, W1r, W2l, W2r, xb, wcat1, wcat2, deg, n8, E, nb_cvt, nb_cnt);
    scan_local<<<nchunks, SCAN_BLK, 0, stream>>>(deg, rowptr, parts, N);
    scan_fin<<<(N + 1 + 255) / 256, 256, 0, stream>>>(rowptr, parts, nchunks, N);
    fill_csr<<<eblk, 256, 0, stream>>>(ei, cursor, rowptr, csr, E);

    const int gemmblk = (N + 127) / 128;
    // Layer 1: h = relu(sage(x)) -> hbuf (bf16)
    sage_layer<true, true><<<gemmblk, 256, 0, stream>>>(
        xb, rowptr, csr, wcat1, b1, hbuf, N);
    // Layer 2: out = sage(h) -> d_out (f32)
    sage_layer<false, false><<<gemmblk, 256, 0, stream>>>(
        hbuf, rowptr, csr, wcat2, b2, out, N);
}

// Round 5
// 287.604 us; speedup vs baseline: 1.3079x; 1.3079x over previous
//
#include <hip/hip_runtime.h>
#include <hip/hip_bf16.h>

// GraphSAGE 2-layer, bf16-MFMA, 9 dispatches.
// sage(feat) = mean_agg(feat) @ Wl^T + feat @ Wr^T + b
// Separate high-TLP gather kernel (2 nodes/half-wave, interleaved chains)
// + two-stage-LDS dual MFMA GEMM ([N,256]@[256,128], K = agg||feat).

#define D 128
#define SCAN_BLK 1024

typedef __attribute__((ext_vector_type(8))) short bf16x8;
typedef __attribute__((ext_vector_type(4))) float f32x4;

__device__ inline ushort f2bf(float f) {
    uint u = __float_as_uint(f);
    u += 0x7FFF + ((u >> 16) & 1);            // round-to-nearest-even
    return (ushort)(u >> 16);
}

// ---------------- setup: count_deg + x->bf16 + pack both weight tables ----------

__global__ __launch_bounds__(256) void setup_all(
        const float* __restrict__ x, const int* __restrict__ ei,
        const float* __restrict__ W1l, const float* __restrict__ W1r,
        const float* __restrict__ W2l, const float* __restrict__ W2r,
        ushort* __restrict__ xb, ushort* __restrict__ wcat1,
        ushort* __restrict__ wcat2, int* __restrict__ deg,
        int n8, int E, int nb_cvt, int nb_cnt) {
    int b = blockIdx.x;
    int tid = threadIdx.x;
    if (b < nb_cvt) {
        // x (f32) -> xb (bf16), 8 elems/thread
        int i = b * 256 + tid;
        if (i >= n8) return;
        const float4* p = (const float4*)x;
        float4 a = p[i * 2], c = p[i * 2 + 1];
        uint4 pk;
        pk.x = (uint)f2bf(a.x) | ((uint)f2bf(a.y) << 16);
        pk.y = (uint)f2bf(a.z) | ((uint)f2bf(a.w) << 16);
        pk.z = (uint)f2bf(c.x) | ((uint)f2bf(c.y) << 16);
        pk.w = (uint)f2bf(c.z) | ((uint)f2bf(c.w) << 16);
        *(uint4*)&xb[i * 8] = pk;
    } else if (b < nb_cvt + nb_cnt) {
        // degree count (dst)
        int e = (b - nb_cvt) * 256 + tid;
        if (e < E) atomicAdd(&deg[ei[E + e]], 1);
    } else {
        // pack Wl||Wr -> wcat[128][256] bf16, both layers. 16384 threads, 4 elems each.
        int t = (b - nb_cvt - nb_cnt) * 256 + tid;
        int layer = t >> 13;                  // 0 or 1
        int tt = t & 8191;
        int e = tt * 4;
        int row = e >> 8;
        int k = e & 255;
        const float* Wl = layer ? W2l : W1l;
        const float* Wr = layer ? W2r : W1r;
        const float* src = (k < 128) ? &Wl[row * 128 + k] : &Wr[row * 128 + k - 128];
        float4 v = *(const float4*)src;
        uint2 pk;
        pk.x = (uint)f2bf(v.x) | ((uint)f2bf(v.y) << 16);
        pk.y = (uint)f2bf(v.z) | ((uint)f2bf(v.w) << 16);
        ushort* wcat = layer ? wcat2 : wcat1;
        *(uint2*)&wcat[e] = pk;
    }
}

// ---------------- CSR scan ----------------

__global__ __launch_bounds__(SCAN_BLK) void scan_local(
        const int* __restrict__ deg, int* __restrict__ rowptr,
        int* __restrict__ partials, int n) {
    __shared__ int sdata[SCAN_BLK];
    int tid = threadIdx.x;
    int i = blockIdx.x * SCAN_BLK + tid;
    int v = (i < n) ? deg[i] : 0;
    sdata[tid] = v;
    __syncthreads();
    #pragma unroll
    for (int off = 1; off < SCAN_BLK; off <<= 1) {
        int t = (tid >= off) ? sdata[tid - off] : 0;
        __syncthreads();
        sdata[tid] += t;
        __syncthreads();
    }
    if (i < n) rowptr[i] = sdata[tid] - v;              // local exclusive
    if (tid == SCAN_BLK - 1) partials[blockIdx.x] = sdata[SCAN_BLK - 1];
}

__global__ __launch_bounds__(256) void scan_fin(
        int* __restrict__ rowptr, const int* __restrict__ partials,
        int nchunks, int n) {
    __shared__ int p[1024];
    int tid = threadIdx.x;
    for (int j = tid; j < nchunks; j += 256) p[j] = partials[j];
    __syncthreads();
    int i = blockIdx.x * 256 + tid;
    if (i > n) return;
    if (i == n) {
        int t = 0;
        for (int j = 0; j < nchunks; ++j) t += p[j];
        rowptr[n] = t;
    } else {
        int c = i >> 10;
        int base = 0;
        for (int j = 0; j < c; ++j) base += p[j];
        rowptr[i] += base;
    }
}

__global__ void fill_csr(const int* __restrict__ ei, int* __restrict__ cursor,
                         const int* __restrict__ rowptr, int* __restrict__ csr, int E) {
    int e = blockIdx.x * 256 + threadIdx.x;
    if (e < E) {
        int s = ei[e];          // src
        int d = ei[E + e];      // dst
        int pos = atomicAdd(&cursor[d], 1);
        csr[rowptr[d] + pos] = s;
    }
}

// ------- mean aggregation: 2 nodes per half-wave, interleaved chains -----------
// 16 gather loads in flight per lane; per-node parallelism preserved (one batch
// round covers deg<=8, 83% of nodes at avg degree 6.25).

__global__ __launch_bounds__(256) void agg_mean_b(
        const ushort* __restrict__ feat, const int* __restrict__ rowptr,
        const int* __restrict__ csr, ushort* __restrict__ aggout, int n, int E) {
    int hw = (blockIdx.x * 256 + threadIdx.x) >> 5;
    int lane = threadIdx.x & 31;
    int n0 = hw * 2, n1 = n0 + 1;
    if (n0 >= n) return;
    int beg0 = rowptr[n0], end0 = rowptr[n0 + 1];
    int beg1 = 0, end1 = 0;
    if (n1 < n) { beg1 = end0; end1 = rowptr[n1 + 1]; }
    int s0 = (beg0 < E) ? beg0 : E - 1;   // safe fallback index
    int s1 = (beg1 < E) ? beg1 : E - 1;

    float a0[4] = {0.f, 0.f, 0.f, 0.f};
    float a1[4] = {0.f, 0.f, 0.f, 0.f};
    int e0 = beg0, e1 = beg1;
    while (e0 < end0 || e1 < end1) {
        uint2 v0[8], v1[8];
        float w0[8], w1[8];
        #pragma unroll
        for (int u = 0; u < 8; ++u) {
            int i0 = e0 + u;
            int src0 = csr[(i0 < end0) ? i0 : s0];
            v0[u] = *(const uint2*)&feat[src0 * D + lane * 4];
            w0[u] = (i0 < end0) ? 1.f : 0.f;
            int i1 = e1 + u;
            int src1 = csr[(i1 < end1) ? i1 : s1];
            v1[u] = *(const uint2*)&feat[src1 * D + lane * 4];
            w1[u] = (i1 < end1) ? 1.f : 0.f;
        }
        #pragma unroll
        for (int u = 0; u < 8; ++u) {
            a0[0] = fmaf(w0[u], __uint_as_float(v0[u].x << 16), a0[0]);
            a0[1] = fmaf(w0[u], __uint_as_float(v0[u].x & 0xFFFF0000u), a0[1]);
            a0[2] = fmaf(w0[u], __uint_as_float(v0[u].y << 16), a0[2]);
            a0[3] = fmaf(w0[u], __uint_as_float(v0[u].y & 0xFFFF0000u), a0[3]);
            a1[0] = fmaf(w1[u], __uint_as_float(v1[u].x << 16), a1[0]);
            a1[1] = fmaf(w1[u], __uint_as_float(v1[u].x & 0xFFFF0000u), a1[1]);
            a1[2] = fmaf(w1[u], __uint_as_float(v1[u].y << 16), a1[2]);
            a1[3] = fmaf(w1[u], __uint_as_float(v1[u].y & 0xFFFF0000u), a1[3]);
        }
        e0 += 8; e1 += 8;
    }
    float inv0 = (end0 > beg0) ? 1.0f / (float)(end0 - beg0) : 0.0f;
    uint2 pk;
    pk.x = (uint)f2bf(a0[0] * inv0) | ((uint)f2bf(a0[1] * inv0) << 16);
    pk.y = (uint)f2bf(a0[2] * inv0) | ((uint)f2bf(a0[3] * inv0) << 16);
    *(uint2*)&aggout[n0 * D + lane * 4] = pk;
    if (n1 < n) {
        float inv1 = (end1 > beg1) ? 1.0f / (float)(end1 - beg1) : 0.0f;
        pk.x = (uint)f2bf(a1[0] * inv1) | ((uint)f2bf(a1[1] * inv1) << 16);
        pk.y = (uint)f2bf(a1[2] * inv1) | ((uint)f2bf(a1[3] * inv1) << 16);
        *(uint2*)&aggout[n1 * D + lane * 4] = pk;
    }
}

// ---------------- MFMA dual GEMM, two-stage 32KB LDS ----------------
// Block: 256 thr (4 waves), 128 rows. Wave w: rows w*32..+31 (2 row-tiles of 16)
// x 128 cols (8 col-tiles). Stage Wl-half (32KB, swizzled), compute kc 0-3 from
// agg; restage Wr-half, compute from feat. Row stride 256B would be 16-way bank
// conflict on ds_read_b128; byte ^= (row&7)<<4 -> 2-way (free, m136).

template <bool OUT_BF16, bool RELU>
__global__ __launch_bounds__(256) void sage_gemm_mfma(
        const ushort* __restrict__ aggb, const ushort* __restrict__ featb,
        const ushort* __restrict__ wcat, const float* __restrict__ bias,
        void* __restrict__ outp, int n) {
    __shared__ char lds[32768];        // one W-half [128 rows][128 k] bf16, swizzled
    int tid = threadIdx.x;
    int wave = tid >> 6, l = tid & 63;
    int l15 = l & 15, lhi = l >> 4;
    int row_base = blockIdx.x * 128 + wave * 32;

    f32x4 zero = {0.f, 0.f, 0.f, 0.f};
    f32x4 acc[2][8];
    #pragma unroll
    for (int t = 0; t < 2; ++t)
        #pragma unroll
        for (int j = 0; j < 8; ++j) acc[t][j] = zero;

    int ra0 = row_base + l15;       if (ra0 > n - 1) ra0 = n - 1;
    int ra1 = row_base + 16 + l15;  if (ra1 > n - 1) ra1 = n - 1;

    #pragma unroll
    for (int half = 0; half < 2; ++half) {
        if (half) __syncthreads();     // all reads of previous half done
        // stage 32KB: 2048 x uint4, 8 per thread
        #pragma unroll
        for (int rep = 0; rep < 8; ++rep) {
            int chunk = tid + rep * 256;          // 0..2047
            int r = chunk >> 4;                   // 16 chunks (256B) per row
            int c = chunk & 15;                   // 16B chunk within row
            int byte = (r << 8) + (c << 4);
            int sb = byte ^ ((r & 7) << 4);
            *(uint4*)&lds[sb] = *(const uint4*)&wcat[r * 256 + half * 128 + c * 8];
        }
        __syncthreads();

        const ushort* asrc = half ? featb : aggb;
        #pragma unroll
        for (int kc = 0; kc < 4; ++kc) {
            int klocal = kc * 32 + lhi * 8;
            bf16x8 a0 = *(const bf16x8*)&asrc[ra0 * D + klocal];
            bf16x8 a1 = *(const bf16x8*)&asrc[ra1 * D + klocal];
            #pragma unroll
            for (int j = 0; j < 8; ++j) {
                int brow = l15 + j * 16;
                int bbyte = (brow << 8) + kc * 64 + lhi * 16;
                bf16x8 b = *(const bf16x8*)&lds[bbyte ^ ((brow & 7) << 4)];
                acc[0][j] = __builtin_amdgcn_mfma_f32_16x16x32_bf16(a0, b, acc[0][j], 0, 0, 0);
                acc[1][j] = __builtin_amdgcn_mfma_f32_16x16x32_bf16(a1, b, acc[1][j], 0, 0, 0);
            }
        }
    }

    // epilogue: C/D layout col = lane&15, row = (lane>>4)*4 + reg
    #pragma unroll
    for (int t = 0; t < 2; ++t) {
        #pragma unroll
        for (int j = 0; j < 8; ++j) {
            int col = j * 16 + l15;
            float bv = bias[col];
            #pragma unroll
            for (int r = 0; r < 4; ++r) {
                int grow = row_base + t * 16 + lhi * 4 + r;
                if (grow >= n) continue;
                float v = acc[t][j][r] + bv;
                if (RELU) v = fmaxf(v, 0.f);
                if (OUT_BF16) ((ushort*)outp)[grow * D + col] = f2bf(v);
                else          ((float*)outp)[grow * D + col] = v;
            }
        }
    }
}

// ---------------- launch ----------------

extern "C" void kernel_launch(void* const* d_in, const int* in_sizes, int n_in,
                              void* d_out, int out_size, void* d_ws, size_t ws_size,
                              hipStream_t stream) {
    const float* x   = (const float*)d_in[0];
    const int*   ei  = (const int*)d_in[1];
    const float* W1l = (const float*)d_in[2];
    const float* b1  = (const float*)d_in[3];
    const float* W1r = (const float*)d_in[4];
    const float* W2l = (const float*)d_in[5];
    const float* b2  = (const float*)d_in[6];
    const float* W2r = (const float*)d_in[7];
    float* out = (float*)d_out;

    const int N = in_sizes[0] / D;
    const int E = in_sizes[1] / 2;

    // workspace layout
    ushort* xb    = (ushort*)d_ws;                        // N*D bf16
    ushort* hbuf  = xb + (size_t)N * D;                   // N*D bf16
    ushort* aggb  = hbuf + (size_t)N * D;                 // N*D bf16
    ushort* wcat1 = aggb + (size_t)N * D;                 // 32768 bf16
    ushort* wcat2 = wcat1 + 32768;                        // 32768 bf16
    int* deg      = (int*)(wcat2 + 32768);                // N
    int* cursor   = deg + N;                              // N (adjacent: 1 memset)
    int* rowptr   = cursor + N;                           // N+1
    int* csr      = rowptr + N + 1;                       // E
    int* parts    = csr + E;                              // 1024

    const int nchunks = (N + SCAN_BLK - 1) / SCAN_BLK;
    const int eblk = (E + 255) / 256;
    const int n8 = N * D / 8;
    const int nb_cvt = (n8 + 255) / 256;
    const int nb_cnt = eblk;
    const int nb_w = 16384 / 256;   // 2 layers * 32768 elems / 4 per thread

    hipMemsetAsync(deg, 0, 2 * (size_t)N * sizeof(int), stream);   // deg + cursor

    setup_all<<<nb_cvt + nb_cnt + nb_w, 256, 0, stream>>>(
        x, ei, W1l, W1r, W2l, W2r, xb, wcat1, wcat2, deg, n8, E, nb_cvt, nb_cnt);
    scan_local<<<nchunks, SCAN_BLK, 0, stream>>>(deg, rowptr, parts, N);
    scan_fin<<<(N + 1 + 255) / 256, 256, 0, stream>>>(rowptr, parts, nchunks, N);
    fill_csr<<<eblk, 256, 0, stream>>>(ei, cursor, rowptr, csr, E);

    const int aggblk = ((N + 1) / 2 * 32 + 255) / 256;    // 2 nodes per half-wave
    const int gemmblk = (N + 127) / 128;

    // Layer 1: h = relu(sage(x)) -> hbuf (bf16)
    agg_mean_b<<<aggblk, 256, 0, stream>>>(xb, rowptr, csr, aggb, N, E);
    sage_gemm_mfma<true, true><<<gemmblk, 256, 0, stream>>>(aggb, xb, wcat1, b1, hbuf, N);

    // Layer 2: out = sage(h) -> d_out (f32)
    agg_mean_b<<<aggblk, 256, 0, stream>>>(hbuf, rowptr, csr, aggb, N, E);
    sage_gemm_mfma<false, false><<<gemmblk, 256, 0, stream>>>(aggb, hbuf, wcat2, b2, out, N);
}